// Round 5
// baseline (253.627 us; speedup 1.0000x reference)
//
#include <hip/hip_runtime.h>

typedef __attribute__((ext_vector_type(8))) short bf16x8;
typedef __attribute__((ext_vector_type(4))) short bf16x4;
typedef __attribute__((ext_vector_type(4))) float f32x4;

#define MFMA(a, b, c) __builtin_amdgcn_mfma_f32_16x16x32_bf16((a), (b), (c), 0, 0, 0)
// async 16B global->LDS (dest = wave-uniform base + lane*16)
#define GLOAD16(g, l)                                                        \
  __builtin_amdgcn_global_load_lds(                                          \
      (const __attribute__((address_space(1))) void*)(g),                    \
      (__attribute__((address_space(3))) void*)(l), 16, 0, 0)

__device__ __forceinline__ unsigned short f2bf(float f) {
  unsigned int x = __float_as_uint(f);
  return (unsigned short)((x + 0x7fffu + ((x >> 16) & 1u)) >> 16);
}
__device__ __forceinline__ unsigned int cvtpk(float lo, float hi) {
  unsigned int r;
  asm("v_cvt_pk_bf16_f32 %0, %1, %2" : "=v"(r) : "v"(lo), "v"(hi));
  return r;
}

constexpr int SEQ = 2048;
constexpr int NH = 8;
constexpr int DH = 128;
constexpr int DIM = 1024;
constexpr float SCALE = 0.08838834764831845f; // 1/sqrt(128)

// ---------------------------------------------------------------------------
// K0: one-shot f32 -> bf16 cast of x (4.19M), qkv_proj (3.15M), w_out (1.05M)
// ---------------------------------------------------------------------------
__global__ __launch_bounds__(256) void k_cast(
    const float* __restrict__ x, const float* __restrict__ wqkv,
    const float* __restrict__ wout, unsigned short* __restrict__ xbf,
    unsigned short* __restrict__ qkvbf, unsigned short* __restrict__ woutbf)
{
  int i = (blockIdx.x * 256 + threadIdx.x) * 8;
  const float* src;
  unsigned short* dst;
  int off;
  if (i < 4194304) { src = x; dst = xbf; off = i; }
  else if (i < 7340032) { src = wqkv; dst = qkvbf; off = i - 4194304; }
  else { src = wout; dst = woutbf; off = i - 7340032; }
  f32x4 a = *(const f32x4*)(src + off);
  f32x4 b = *(const f32x4*)(src + off + 4);
  uint4 u;
  u.x = cvtpk(a[0], a[1]); u.y = cvtpk(a[2], a[3]);
  u.z = cvtpk(b[0], b[1]); u.w = cvtpk(b[2], b[3]);
  *(uint4*)(dst + off) = u;
}

// ---------------------------------------------------------------------------
// K1: qkv = x @ qkv_proj^T (M=4096,N=3072,K=1024) on pre-cast bf16, staged via
// global_load_lds into linear [128][32] LDS. Fused RoPE epilogue.
// ---------------------------------------------------------------------------
__global__ __launch_bounds__(256) void k_qkv_rope(
    const unsigned short* __restrict__ xbf, const unsigned short* __restrict__ wbf,
    const float* __restrict__ cosT, const float* __restrict__ sinT,
    unsigned short* __restrict__ q, unsigned short* __restrict__ k,
    unsigned short* __restrict__ vT)
{
  __shared__ __align__(16) unsigned short As[128 * 32]; // linear, 8 KB
  __shared__ __align__(16) unsigned short Bs[128 * 32];
  const int tid = threadIdx.x;
  const int wave = tid >> 6, lane = tid & 63;
  const int fr = lane & 15, fq = lane >> 4;
  const int fk = fq * 8;
  const int wr = (wave >> 1) * 64, wc = (wave & 1) * 64;
  const int m0 = blockIdx.x * 128, n0 = blockIdx.y * 128;
  const int lrow = lane >> 2, lcol = (lane & 3) * 8; // 16 rows x 64B per slab

  const unsigned short* gA0 = xbf + (m0 + wave * 32 + lrow) * 1024 + lcol;
  const unsigned short* gA1 = gA0 + 16 * 1024;
  const unsigned short* gB0 = wbf + (n0 + wave * 32 + lrow) * 1024 + lcol;
  const unsigned short* gB1 = gB0 + 16 * 1024;
  unsigned short* lA = &As[wave * 32 * 32]; // wave-uniform base
  unsigned short* lB = &Bs[wave * 32 * 32];

  f32x4 zero4 = {0.f, 0.f, 0.f, 0.f};
  f32x4 acc[4][4];
  for (int i = 0; i < 4; ++i)
    for (int j = 0; j < 4; ++j) acc[i][j] = zero4;

  for (int kt = 0; kt < 32; ++kt) {
    const int k0 = kt * 32;
    GLOAD16(gA0 + k0, lA);
    GLOAD16(gA1 + k0, lA + 512);
    GLOAD16(gB0 + k0, lB);
    GLOAD16(gB1 + k0, lB + 512);
    __syncthreads(); // drains vmcnt -> LDS ready
    bf16x8 af[4], bfr[4];
#pragma unroll
    for (int mi = 0; mi < 4; ++mi) af[mi] = *(const bf16x8*)&As[(wr + mi * 16 + fr) * 32 + fk];
#pragma unroll
    for (int ni = 0; ni < 4; ++ni) bfr[ni] = *(const bf16x8*)&Bs[(wc + ni * 16 + fr) * 32 + fk];
    __builtin_amdgcn_s_setprio(1);
#pragma unroll
    for (int mi = 0; mi < 4; ++mi)
#pragma unroll
      for (int ni = 0; ni < 4; ++ni)
        acc[mi][ni] = MFMA(af[mi], bfr[ni], acc[mi][ni]);
    __builtin_amdgcn_s_setprio(0);
    __syncthreads(); // all reads done before next overwrite
  }

  // epilogue: D layout col=lane&15, row=(lane>>4)*4+r. RoPE via shfl_xor(1).
#pragma unroll
  for (int mi = 0; mi < 4; ++mi)
#pragma unroll
    for (int ni = 0; ni < 4; ++ni)
#pragma unroll
      for (int r = 0; r < 4; ++r) {
        float val = acc[mi][ni][r];
        float other = __shfl_xor(val, 1, 64);
        int m = m0 + wr + mi * 16 + fq * 4 + r;
        int n = n0 + wc + ni * 16 + fr;
        int a = n >> 10, feat = n & 1023;
        int hh = feat >> 7, dh = feat & 127;
        int bi = m >> 11, t = m & 2047;
        if (a == 2) {
          vT[((bi * NH + hh) * DH + dh) * SEQ + t] = f2bf(val);
        } else {
          float c = cosT[t * 64 + (dh >> 1)];
          float s = sinT[t * 64 + (dh >> 1)];
          float o = ((dh & 1) == 0) ? (val * c - other * s) : (other * s + val * c);
          unsigned short* dst = (a == 0) ? q : k;
          dst[((bi * NH + hh) * SEQ + t) * DH + dh] = f2bf(o);
        }
      }
}

// ---------------------------------------------------------------------------
// K2: causal attention per (b, head, 64-row tile). 64-col K/V tiles.
// Pass A: rowsums. Pass B: recompute + f32 attn + PV. Tail: zero-fill.
// ---------------------------------------------------------------------------
__global__ __launch_bounds__(256) void k_attn(
    const unsigned short* __restrict__ q, const unsigned short* __restrict__ k,
    const unsigned short* __restrict__ vT,
    float* __restrict__ attn, unsigned short* __restrict__ heads)
{
  __shared__ __align__(16) unsigned short Kt[64][140];
  __shared__ __align__(16) unsigned short Vt[128][76];
  __shared__ __align__(16) unsigned short Esc[4][16][76];

  const int tid = threadIdx.x;
  const int wave = tid >> 6, lane = tid & 63;
  const int fr = lane & 15, fq = lane >> 4;
  const int fk = fq * 8;
  const int rt = (blockIdx.z == 0) ? (int)blockIdx.x : (31 - (int)blockIdx.x);
  const int row0 = rt * 64;
  const int hh = blockIdx.y, bi = blockIdx.z;
  const int bh = bi * NH + hh;
  const int r0 = row0 + wave * 16;

  const unsigned short* qb = q + bh * SEQ * DH;
  const unsigned short* kb = k + bh * SEQ * DH;
  const unsigned short* vb = vT + bh * DH * SEQ;

  bf16x8 aq[4];
#pragma unroll
  for (int ks = 0; ks < 4; ++ks)
    aq[ks] = *(const bf16x8*)(qb + (r0 + fr) * DH + ks * 32 + fk);

  const int wmax = r0 + 15;
  float rs[4] = {0.f, 0.f, 0.f, 0.f};

  // ---- pass A: row sums ----
  for (int nt = 0; nt <= rt; ++nt) {
    const int c0 = nt * 64;
    __syncthreads();
#pragma unroll
    for (int j = 0; j < 4; ++j) {
      int f = j * 256 + tid;
      int r = f >> 4, c = (f & 15) * 8;
      *(bf16x8*)&Kt[r][c] = *(const bf16x8*)(kb + (c0 + r) * DH + c);
    }
    __syncthreads();
#pragma unroll
    for (int half = 0; half < 4; ++half) {
      int ch = c0 + half * 16;
      if (ch <= wmax) {
        f32x4 s = {0.f, 0.f, 0.f, 0.f};
        __builtin_amdgcn_s_setprio(1);
#pragma unroll
        for (int ks = 0; ks < 4; ++ks) {
          bf16x8 bk = *(const bf16x8*)&Kt[half * 16 + fr][ks * 32 + fk];
          s = MFMA(aq[ks], bk, s);
        }
        __builtin_amdgcn_s_setprio(0);
        int col = ch + fr;
#pragma unroll
        for (int r = 0; r < 4; ++r) {
          int row = r0 + fq * 4 + r;
          if (col <= row) rs[r] += __expf(s[r] * SCALE);
        }
      }
    }
  }

#pragma unroll
  for (int r = 0; r < 4; ++r)
#pragma unroll
    for (int msk = 1; msk < 16; msk <<= 1)
      rs[r] += __shfl_xor(rs[r], msk, 64);

  float inv[4];
#pragma unroll
  for (int r = 0; r < 4; ++r) inv[r] = 1.0f / rs[r];

  f32x4 pv[8];
  {
    f32x4 zero4 = {0.f, 0.f, 0.f, 0.f};
#pragma unroll
    for (int i = 0; i < 8; ++i) pv[i] = zero4;
  }

  // ---- pass B: normalized attn write (f32) + PV ----
  for (int nt = 0; nt <= rt; ++nt) {
    const int c0 = nt * 64;
    __syncthreads();
#pragma unroll
    for (int j = 0; j < 4; ++j) {
      int f = j * 256 + tid;
      int r = f >> 4, c = (f & 15) * 8;
      *(bf16x8*)&Kt[r][c] = *(const bf16x8*)(kb + (c0 + r) * DH + c);
      int rv = f >> 3, cv = (f & 7) * 8;
      *(bf16x8*)&Vt[rv][cv] = *(const bf16x8*)(vb + rv * SEQ + c0 + cv);
    }
    __syncthreads();
#pragma unroll
    for (int half = 0; half < 4; ++half) {
      int ch = c0 + half * 16;
      bool live = (ch <= wmax);
      f32x4 s = {0.f, 0.f, 0.f, 0.f};
      if (live) {
        __builtin_amdgcn_s_setprio(1);
#pragma unroll
        for (int ks = 0; ks < 4; ++ks) {
          bf16x8 bk = *(const bf16x8*)&Kt[half * 16 + fr][ks * 32 + fk];
          s = MFMA(aq[ks], bk, s);
        }
        __builtin_amdgcn_s_setprio(0);
      }
      int col = ch + fr;
#pragma unroll
      for (int r = 0; r < 4; ++r) {
        int row = r0 + fq * 4 + r;
        float p = (live && col <= row) ? __expf(s[r] * SCALE) * inv[r] : 0.f;
        attn[((size_t)bh * SEQ + row) * SEQ + col] = p;
        Esc[wave][fq * 4 + r][half * 16 + fr] = f2bf(p);
      }
    }
    bf16x8 ae0 = *(const bf16x8*)&Esc[wave][fr][fk];
    bf16x8 ae1 = *(const bf16x8*)&Esc[wave][fr][32 + fk];
    __builtin_amdgcn_s_setprio(1);
#pragma unroll
    for (int ni = 0; ni < 8; ++ni) {
      bf16x8 bv0 = *(const bf16x8*)&Vt[ni * 16 + fr][fk];
      bf16x8 bv1 = *(const bf16x8*)&Vt[ni * 16 + fr][32 + fk];
      pv[ni] = MFMA(ae0, bv0, pv[ni]);
      pv[ni] = MFMA(ae1, bv1, pv[ni]);
    }
    __builtin_amdgcn_s_setprio(0);
  }

#pragma unroll
  for (int ni = 0; ni < 8; ++ni)
#pragma unroll
    for (int r = 0; r < 4; ++r) {
      int row = r0 + fq * 4 + r;
      int dh = ni * 16 + fr;
      heads[(bi * SEQ + row) * DIM + hh * DH + dh] = f2bf(pv[ni][r]);
    }

  // ---- tail: zero cols [row0+64, 2048) ----
  {
    const int zstart = row0 + 64;
    f32x4 z4 = {0.f, 0.f, 0.f, 0.f};
#pragma unroll
    for (int rr = 0; rr < 4; ++rr) {
      int row = r0 + rr * 4 + fq;
      float* dst = attn + ((size_t)bh * SEQ + row) * SEQ;
      for (int c = zstart + fr * 4; c < SEQ; c += 64)
        *(f32x4*)(dst + c) = z4;
    }
  }
}

// ---------------------------------------------------------------------------
// K3: out = heads @ w_out^T (M=4096,N=1024,K=1024), bf16 sources via
// global_load_lds, f32 output.
// ---------------------------------------------------------------------------
__global__ __launch_bounds__(256) void k_outproj(
    const unsigned short* __restrict__ heads, const unsigned short* __restrict__ wbf,
    float* __restrict__ out)
{
  __shared__ __align__(16) unsigned short As[128 * 32];
  __shared__ __align__(16) unsigned short Bs[128 * 32];
  const int tid = threadIdx.x;
  const int wave = tid >> 6, lane = tid & 63;
  const int fr = lane & 15, fq = lane >> 4;
  const int fk = fq * 8;
  const int wr = (wave >> 1) * 64, wc = (wave & 1) * 64;
  const int m0 = blockIdx.x * 128, n0 = blockIdx.y * 128;
  const int lrow = lane >> 2, lcol = (lane & 3) * 8;

  const unsigned short* gA0 = heads + (m0 + wave * 32 + lrow) * 1024 + lcol;
  const unsigned short* gA1 = gA0 + 16 * 1024;
  const unsigned short* gB0 = wbf + (n0 + wave * 32 + lrow) * 1024 + lcol;
  const unsigned short* gB1 = gB0 + 16 * 1024;
  unsigned short* lA = &As[wave * 32 * 32];
  unsigned short* lB = &Bs[wave * 32 * 32];

  f32x4 zero4 = {0.f, 0.f, 0.f, 0.f};
  f32x4 acc[4][4];
  for (int i = 0; i < 4; ++i)
    for (int j = 0; j < 4; ++j) acc[i][j] = zero4;

  for (int kt = 0; kt < 32; ++kt) {
    const int k0 = kt * 32;
    GLOAD16(gA0 + k0, lA);
    GLOAD16(gA1 + k0, lA + 512);
    GLOAD16(gB0 + k0, lB);
    GLOAD16(gB1 + k0, lB + 512);
    __syncthreads();
    bf16x8 af[4], bfr[4];
#pragma unroll
    for (int mi = 0; mi < 4; ++mi) af[mi] = *(const bf16x8*)&As[(wr + mi * 16 + fr) * 32 + fk];
#pragma unroll
    for (int ni = 0; ni < 4; ++ni) bfr[ni] = *(const bf16x8*)&Bs[(wc + ni * 16 + fr) * 32 + fk];
    __builtin_amdgcn_s_setprio(1);
#pragma unroll
    for (int mi = 0; mi < 4; ++mi)
#pragma unroll
      for (int ni = 0; ni < 4; ++ni)
        acc[mi][ni] = MFMA(af[mi], bfr[ni], acc[mi][ni]);
    __builtin_amdgcn_s_setprio(0);
    __syncthreads();
  }

#pragma unroll
  for (int mi = 0; mi < 4; ++mi)
#pragma unroll
    for (int ni = 0; ni < 4; ++ni)
#pragma unroll
      for (int r = 0; r < 4; ++r) {
        int m = m0 + wr + mi * 16 + fq * 4 + r;
        int n = n0 + wc + ni * 16 + fr;
        out[m * 1024 + n] = acc[mi][ni][r];
      }
}

extern "C" void kernel_launch(void* const* d_in, const int* in_sizes, int n_in,
                              void* d_out, int out_size, void* d_ws, size_t ws_size,
                              hipStream_t stream)
{
  const float* x    = (const float*)d_in[0];
  const float* wqkv = (const float*)d_in[1];
  const float* wout = (const float*)d_in[2];
  const float* cosT = (const float*)d_in[3];
  const float* sinT = (const float*)d_in[4];

  float* out  = (float*)d_out;
  float* attn = out + 4194304;
  unsigned short* ws = (unsigned short*)d_ws;
  unsigned short* q      = ws;             // (B,H,T,DH) bf16
  unsigned short* kk     = ws + 4194304;   // (B,H,T,DH) bf16
  unsigned short* vT     = ws + 8388608;   // (B,H,DH,T) bf16
  unsigned short* heads  = ws + 12582912;  // (B,T,DIM) bf16
  unsigned short* xbf    = ws + 16777216;  // (B,T,DIM) bf16
  unsigned short* qkvbf  = ws + 20971520;  // (3*1024,1024) bf16
  unsigned short* woutbf = ws + 24117248;  // (1024,1024) bf16

  k_cast<<<4096, 256, 0, stream>>>(x, wqkv, wout, xbf, qkvbf, woutbf);
  k_qkv_rope<<<dim3(32, 24), 256, 0, stream>>>(xbf, qkvbf, cosT, sinT, q, kk, vT);
  k_attn<<<dim3(32, 8, 2), 256, 0, stream>>>(q, kk, vT, attn, heads);
  k_outproj<<<dim3(32, 8), 256, 0, stream>>>(heads, woutbf, out);
}